// Round 1
// baseline (281.702 us; speedup 1.0000x reference)
//
#include <hip/hip_runtime.h>
#include <math.h>

#define NSRC 1000
#define NTGT 100
#define NCLS 256
#define NB   32
#define NSP  1024                 // padded column count for LSA
#define PAD_IDX(j) ((j) + ((j) >> 4))
#define LDSN (NSP + (NSP >> 4))   // 1088 padded LDS entries

// ---------------- per-(b,s) logsumexp over 256 classes: 1 wave per row ------
__global__ __launch_bounds__(64) void lse_kernel(const float* __restrict__ logits,
                                                 float* __restrict__ lse) {
    int row  = blockIdx.x;            // b*NSRC + s
    int lane = threadIdx.x;
    float4 v4 = reinterpret_cast<const float4*>(logits + (size_t)row * NCLS)[lane];
    float m = fmaxf(fmaxf(v4.x, v4.y), fmaxf(v4.z, v4.w));
    #pragma unroll
    for (int off = 32; off >= 1; off >>= 1) m = fmaxf(m, __shfl_xor(m, off));
    float s = expf(v4.x - m) + expf(v4.y - m) + expf(v4.z - m) + expf(v4.w - m);
    #pragma unroll
    for (int off = 32; off >= 1; off >>= 1) s += __shfl_xor(s, off);
    if (lane == 0) lse[row] = m + logf(s);
}

// ---------------- transposed cost matrix: one block per (b,t) row -----------
__global__ __launch_bounds__(256) void cost_kernel(const float* __restrict__ logits,
                                                   const int*   __restrict__ tcls,
                                                   const float* __restrict__ sbox,
                                                   const float* __restrict__ tbox,
                                                   const float* __restrict__ lse,
                                                   float*       __restrict__ cost) {
    int bt = blockIdx.x;              // b*NTGT + t
    int b  = bt / NTGT;
    int cls = tcls[bt];
    float4 tb = reinterpret_cast<const float4*>(tbox)[bt];
    float area_t = (tb.z - tb.x) * (tb.w - tb.y);
    float* crow = cost + (size_t)bt * NSP;
    for (int s = threadIdx.x; s < NSP; s += 256) {
        if (s >= NSRC) { crow[s] = 1e30f; continue; }
        int gs = b * NSRC + s;
        float4 sb = reinterpret_cast<const float4*>(sbox)[gs];
        float ce = lse[gs] - logits[(size_t)gs * NCLS + cls];
        float ix1 = fmaxf(sb.x, tb.x), iy1 = fmaxf(sb.y, tb.y);
        float ix2 = fminf(sb.z, tb.z), iy2 = fminf(sb.w, tb.w);
        float inter = fmaxf(ix2 - ix1, 0.f) * fmaxf(iy2 - iy1, 0.f);
        float area_s = (sb.z - sb.x) * (sb.w - sb.y);
        float uni = area_s + area_t - inter;
        float iou = inter / uni;
        float cx1 = fminf(sb.x, tb.x), cy1 = fminf(sb.y, tb.y);
        float cx2 = fmaxf(sb.z, tb.z), cy2 = fmaxf(sb.w, tb.w);
        float carea = (cx2 - cx1) * (cy2 - cy1);
        float giou = iou - (carea - uni) / carea;
        float l1 = 0.25f * (fabsf(sb.x - tb.x) + fabsf(sb.y - tb.y) +
                            fabsf(sb.z - tb.z) + fabsf(sb.w - tb.w));
        crow[s] = ce + 10.0f * (1.0f - giou) + l1;
    }
}

// ---------------- Jonker-Volgenant shortest augmenting path -----------------
// One wave per batch. Rows = 100 targets, cols = 1000 (padded 1024) sources.
// Frozen-dual Dijkstra form (equivalent to e-maxx JV, duals updated once per
// augmentation). Per-lane registers: d[16], v[16], used bitmask (16 cols/lane,
// blocked). LDS (stride-17 padded): way/pred, pcol (col -> assigned row),
// uu (col -> u of its assigned row).
__global__ __launch_bounds__(64) void lsa_kernel(const float* __restrict__ cost,
                                                 float* __restrict__ out) {
    int b    = blockIdx.x;
    int lane = threadIdx.x;
    const float* C = cost + (size_t)b * NTGT * NSP;
    __shared__ int   way[LDSN];
    __shared__ int   pcol[LDSN];
    __shared__ float uu[LDSN];
    for (int t = lane; t < LDSN; t += 64) { pcol[t] = -1; uu[t] = 0.f; }
    float v[16], d[16];
    #pragma unroll
    for (int k = 0; k < 16; ++k) v[k] = 0.f;
    int base = lane * 16;
    __syncthreads();

    for (int i = 0; i < NTGT; ++i) {
        // init distances from free row i: d[j] = c[i][j] - v[j]  (u[i] = 0)
        {
            const float4* row4 = reinterpret_cast<const float4*>(C + (size_t)i * NSP + base);
            #pragma unroll
            for (int q = 0; q < 4; ++q) {
                float4 c4 = row4[q];
                d[4*q+0] = c4.x - v[4*q+0];
                d[4*q+1] = c4.y - v[4*q+1];
                d[4*q+2] = c4.z - v[4*q+2];
                d[4*q+3] = c4.w - v[4*q+3];
            }
        }
        #pragma unroll
        for (int k = 0; k < 16; ++k) way[PAD_IDX(base + k)] = -1;
        unsigned int used = 0;
        float Df = 0.f;
        int jf = -1;

        for (int it = 0; it < NTGT + 3; ++it) {
            // argmin of d over non-scanned columns
            float lmin = 1e38f;
            #pragma unroll
            for (int k = 0; k < 16; ++k) {
                float val = ((used >> k) & 1u) ? 1e38f : d[k];
                lmin = fminf(lmin, val);
            }
            float wmin = lmin;
            #pragma unroll
            for (int off = 32; off >= 1; off >>= 1) wmin = fminf(wmin, __shfl_xor(wmin, off));
            unsigned long long msk = __ballot(lmin == wmin);
            int src = __ffsll(msk) - 1;
            int myk = -1;
            #pragma unroll
            for (int k = 15; k >= 0; --k)
                if (!((used >> k) & 1u) && d[k] == wmin) myk = k;
            int j0 = __shfl(base + myk, src);
            if (j0 < 0) break;                    // NaN safety net
            int pj0 = pcol[PAD_IDX(j0)];
            if (pj0 < 0) { Df = wmin; jf = j0; break; }   // reached a free column
            if ((j0 >> 4) == lane) used |= 1u << (j0 & 15);
            float uref = uu[PAD_IDX(j0)];
            float sft  = wmin - uref;             // dist(j0) - u[row(j0)]
            // relax through row pj0
            const float4* rr = reinterpret_cast<const float4*>(C + (size_t)pj0 * NSP + base);
            float cr[16];
            #pragma unroll
            for (int q = 0; q < 4; ++q) {
                float4 c4 = rr[q];
                cr[4*q+0] = c4.x; cr[4*q+1] = c4.y; cr[4*q+2] = c4.z; cr[4*q+3] = c4.w;
            }
            #pragma unroll
            for (int k = 0; k < 16; ++k) {
                float cand = sft + cr[k] - v[k];
                bool upd = (cand < d[k]) && !((used >> k) & 1u);
                if (upd) { d[k] = cand; way[PAD_IDX(base + k)] = j0; }
            }
        }

        // dual updates for scanned columns: v -= (Df - d), u[row] += (Df - d)
        if (jf >= 0) {
            #pragma unroll
            for (int k = 0; k < 16; ++k) {
                if ((used >> k) & 1u) {
                    float diff = Df - d[k];
                    v[k] -= diff;
                    uu[PAD_IDX(base + k)] += diff;
                }
            }
        }
        __syncthreads();
        // augment: walk predecessor chain, shifting rows (and their u) forward
        if (lane == 0 && jf >= 0) {
            int j = jf;
            for (int g = 0; g < NSP; ++g) {
                int jp = way[PAD_IDX(j)];
                if (jp < 0) { pcol[PAD_IDX(j)] = i; uu[PAD_IDX(j)] = Df; break; }
                pcol[PAD_IDX(j)] = pcol[PAD_IDX(jp)];
                uu[PAD_IDX(j)]   = uu[PAD_IDX(jp)];
                j = jp;
            }
        }
        __syncthreads();
    }

    // mean of matched costs
    float acc = 0.f;
    #pragma unroll
    for (int k = 0; k < 16; ++k) {
        int j = base + k;
        if (j < NSRC) {
            int r = pcol[PAD_IDX(j)];
            if (r >= 0) acc += C[(size_t)r * NSP + j];
        }
    }
    #pragma unroll
    for (int off = 32; off >= 1; off >>= 1) acc += __shfl_xor(acc, off);
    if (lane == 0) out[b] = acc * (1.0f / NTGT);
}

extern "C" void kernel_launch(void* const* d_in, const int* in_sizes, int n_in,
                              void* d_out, int out_size, void* d_ws, size_t ws_size,
                              hipStream_t stream) {
    const float* logits = (const float*)d_in[0];   // (32,1000,256) f32
    const int*   tcls   = (const int*)  d_in[1];   // (32,100) i32
    const float* sbox   = (const float*)d_in[2];   // (32,1000,4) f32
    const float* tbox   = (const float*)d_in[3];   // (32,100,4) f32
    float* out = (float*)d_out;                    // (32,) f32

    float* lse  = (float*)d_ws;                    // 32768 floats (32000 used)
    float* cost = lse + 32768;                     // 32*100*1024 floats (~12.8 MB)

    lse_kernel <<<NB * NSRC, 64,  0, stream>>>(logits, lse);
    cost_kernel<<<NB * NTGT, 256, 0, stream>>>(logits, tcls, sbox, tbox, lse, cost);
    lsa_kernel <<<NB,        64,  0, stream>>>(cost, out);
}

// Round 2
// 215.238 us; speedup vs baseline: 1.3088x; 1.3088x over previous
//
#include <hip/hip_runtime.h>
#include <math.h>

#define NSRC 1000
#define NTGT 100
#define NCLS 256
#define NB   32
#define NSP  1024                 // padded column count for LSA
#define PAD_IDX(j) ((j) + ((j) >> 4))
#define LDSN (NSP + (NSP >> 4))   // 1088 padded LDS entries

// ---------------- per-(b,s) logsumexp over 256 classes: 1 wave per row ------
__global__ __launch_bounds__(64) void lse_kernel(const float* __restrict__ logits,
                                                 float* __restrict__ lse) {
    int row  = blockIdx.x;            // b*NSRC + s
    int lane = threadIdx.x;
    float4 v4 = reinterpret_cast<const float4*>(logits + (size_t)row * NCLS)[lane];
    float m = fmaxf(fmaxf(v4.x, v4.y), fmaxf(v4.z, v4.w));
    #pragma unroll
    for (int off = 32; off >= 1; off >>= 1) m = fmaxf(m, __shfl_xor(m, off));
    float s = expf(v4.x - m) + expf(v4.y - m) + expf(v4.z - m) + expf(v4.w - m);
    #pragma unroll
    for (int off = 32; off >= 1; off >>= 1) s += __shfl_xor(s, off);
    if (lane == 0) lse[row] = m + logf(s);
}

// ---------------- transposed cost matrix: one block per (b,t) row -----------
__global__ __launch_bounds__(256) void cost_kernel(const float* __restrict__ logits,
                                                   const int*   __restrict__ tcls,
                                                   const float* __restrict__ sbox,
                                                   const float* __restrict__ tbox,
                                                   const float* __restrict__ lse,
                                                   float*       __restrict__ cost) {
    int bt = blockIdx.x;              // b*NTGT + t
    int b  = bt / NTGT;
    int cls = tcls[bt];
    float4 tb = reinterpret_cast<const float4*>(tbox)[bt];
    float area_t = (tb.z - tb.x) * (tb.w - tb.y);
    float* crow = cost + (size_t)bt * NSP;
    for (int s = threadIdx.x; s < NSP; s += 256) {
        if (s >= NSRC) { crow[s] = 1e30f; continue; }
        int gs = b * NSRC + s;
        float4 sb = reinterpret_cast<const float4*>(sbox)[gs];
        float ce = lse[gs] - logits[(size_t)gs * NCLS + cls];
        float ix1 = fmaxf(sb.x, tb.x), iy1 = fmaxf(sb.y, tb.y);
        float ix2 = fminf(sb.z, tb.z), iy2 = fminf(sb.w, tb.w);
        float inter = fmaxf(ix2 - ix1, 0.f) * fmaxf(iy2 - iy1, 0.f);
        float area_s = (sb.z - sb.x) * (sb.w - sb.y);
        float uni = area_s + area_t - inter;
        float iou = inter / uni;
        float cx1 = fminf(sb.x, tb.x), cy1 = fminf(sb.y, tb.y);
        float cx2 = fmaxf(sb.z, tb.z), cy2 = fmaxf(sb.w, tb.w);
        float carea = (cx2 - cx1) * (cy2 - cy1);
        float giou = iou - (carea - uni) / carea;
        float l1 = 0.25f * (fabsf(sb.x - tb.x) + fabsf(sb.y - tb.y) +
                            fabsf(sb.z - tb.z) + fabsf(sb.w - tb.w));
        crow[s] = ce + 10.0f * (1.0f - giou) + l1;
    }
}

// ---------------- Jonker-Volgenant with greedy row-reduction ----------------
// One wave per batch. Rows = 100 targets, cols = 1000 (padded 1024) sources.
// Phase 1 (greedy row reduction): u[i] = min_j c[i][j]; claim argmin column.
//   ~95/100 rows resolve here; duals stay feasible (c-u-v>=0, =0 on matched).
// Phase 2 (frozen-dual Dijkstra): only for collision-loser rows.
__global__ __launch_bounds__(64) void lsa_kernel(const float* __restrict__ cost,
                                                 float* __restrict__ out) {
    int b    = blockIdx.x;
    int lane = threadIdx.x;
    const float* C = cost + (size_t)b * NTGT * NSP;
    __shared__ int   way[LDSN];     // pred chain; reused as claim[] in phase 1
    __shared__ int   pcol[LDSN];    // col -> assigned row
    __shared__ float uu[LDSN];      // col -> u of its assigned row
    __shared__ float urow[NTGT];    // row min (u dual)
    __shared__ int   jmin[NTGT];    // row argmin column
    __shared__ int   done[NTGT];    // assigned in phase 1?
    for (int t = lane; t < LDSN; t += 64) { pcol[t] = -1; uu[t] = 0.f; way[t] = 0x7fffffff; }
    float v[16], d[16];
    #pragma unroll
    for (int k = 0; k < 16; ++k) v[k] = 0.f;
    int base = lane * 16;
    __syncthreads();

    // ---- Phase 1: per-row min + argmin (independent rows -> pipelined loads)
    #pragma unroll 2
    for (int i = 0; i < NTGT; ++i) {
        const float4* row4 = reinterpret_cast<const float4*>(C + (size_t)i * NSP + base);
        float cr[16];
        #pragma unroll
        for (int q = 0; q < 4; ++q) {
            float4 c4 = row4[q];
            cr[4*q+0] = c4.x; cr[4*q+1] = c4.y; cr[4*q+2] = c4.z; cr[4*q+3] = c4.w;
        }
        float lm = 1e38f; int li = base;
        #pragma unroll
        for (int k = 0; k < 16; ++k)
            if (cr[k] < lm) { lm = cr[k]; li = base + k; }
        float wm = lm;
        #pragma unroll
        for (int off = 32; off >= 1; off >>= 1) wm = fminf(wm, __shfl_xor(wm, off));
        unsigned long long msk = __ballot(lm == wm);
        int src = __ffsll(msk) - 1;
        int wj  = __shfl(li, src);
        if (lane == 0) { urow[i] = wm; jmin[i] = wj; }
    }
    __syncthreads();
    // ---- Phase 1b: claim argmin columns (lowest row index wins)
    for (int r = lane; r < NTGT; r += 64) atomicMin(&way[PAD_IDX(jmin[r])], r);
    __syncthreads();
    for (int r = lane; r < NTGT; r += 64) {
        int j = jmin[r];
        int w = (way[PAD_IDX(j)] == r) ? 1 : 0;
        done[r] = w;
        if (w) { pcol[PAD_IDX(j)] = r; uu[PAD_IDX(j)] = urow[r]; }
    }
    __syncthreads();

    // ---- Phase 2: shortest augmenting path for unassigned rows
    for (int i = 0; i < NTGT; ++i) {
        if (done[i]) continue;                 // uniform across wave (LDS broadcast)
        float ui = urow[i];
        {
            const float4* row4 = reinterpret_cast<const float4*>(C + (size_t)i * NSP + base);
            #pragma unroll
            for (int q = 0; q < 4; ++q) {
                float4 c4 = row4[q];
                d[4*q+0] = c4.x - ui - v[4*q+0];
                d[4*q+1] = c4.y - ui - v[4*q+1];
                d[4*q+2] = c4.z - ui - v[4*q+2];
                d[4*q+3] = c4.w - ui - v[4*q+3];
            }
        }
        #pragma unroll
        for (int k = 0; k < 16; ++k) way[PAD_IDX(base + k)] = -1;
        unsigned int used = 0;
        float Df = 0.f;
        int jf = -1;

        for (int it = 0; it < NTGT + 3; ++it) {
            float lmin = 1e38f;
            #pragma unroll
            for (int k = 0; k < 16; ++k) {
                float val = ((used >> k) & 1u) ? 1e38f : d[k];
                lmin = fminf(lmin, val);
            }
            float wmin = lmin;
            #pragma unroll
            for (int off = 32; off >= 1; off >>= 1) wmin = fminf(wmin, __shfl_xor(wmin, off));
            unsigned long long msk = __ballot(lmin == wmin);
            int src = __ffsll(msk) - 1;
            int myk = -1;
            #pragma unroll
            for (int k = 15; k >= 0; --k)
                if (!((used >> k) & 1u) && d[k] == wmin) myk = k;
            int j0 = __shfl(base + myk, src);
            if (j0 < 0) break;                    // NaN safety net
            int pj0 = pcol[PAD_IDX(j0)];
            if (pj0 < 0) { Df = wmin; jf = j0; break; }   // reached a free column
            if ((j0 >> 4) == lane) used |= 1u << (j0 & 15);
            float uref = uu[PAD_IDX(j0)];
            float sft  = wmin - uref;             // dist(j0) - u[row(j0)]
            const float4* rr = reinterpret_cast<const float4*>(C + (size_t)pj0 * NSP + base);
            float cr[16];
            #pragma unroll
            for (int q = 0; q < 4; ++q) {
                float4 c4 = rr[q];
                cr[4*q+0] = c4.x; cr[4*q+1] = c4.y; cr[4*q+2] = c4.z; cr[4*q+3] = c4.w;
            }
            #pragma unroll
            for (int k = 0; k < 16; ++k) {
                float cand = sft + cr[k] - v[k];
                bool upd = (cand < d[k]) && !((used >> k) & 1u);
                if (upd) { d[k] = cand; way[PAD_IDX(base + k)] = j0; }
            }
        }

        // dual updates for scanned columns: v -= (Df - d), u[row] += (Df - d)
        if (jf >= 0) {
            #pragma unroll
            for (int k = 0; k < 16; ++k) {
                if ((used >> k) & 1u) {
                    float diff = Df - d[k];
                    v[k] -= diff;
                    uu[PAD_IDX(base + k)] += diff;
                }
            }
        }
        __syncthreads();
        // augment: walk predecessor chain, shifting rows (and their u) forward
        if (lane == 0 && jf >= 0) {
            int j = jf;
            for (int g = 0; g < NSP; ++g) {
                int jp = way[PAD_IDX(j)];
                if (jp < 0) { pcol[PAD_IDX(j)] = i; uu[PAD_IDX(j)] = ui + Df; break; }
                pcol[PAD_IDX(j)] = pcol[PAD_IDX(jp)];
                uu[PAD_IDX(j)]   = uu[PAD_IDX(jp)];
                j = jp;
            }
        }
        __syncthreads();
    }

    // mean of matched costs
    float acc = 0.f;
    #pragma unroll
    for (int k = 0; k < 16; ++k) {
        int j = base + k;
        if (j < NSRC) {
            int r = pcol[PAD_IDX(j)];
            if (r >= 0) acc += C[(size_t)r * NSP + j];
        }
    }
    #pragma unroll
    for (int off = 32; off >= 1; off >>= 1) acc += __shfl_xor(acc, off);
    if (lane == 0) out[b] = acc * (1.0f / NTGT);
}

extern "C" void kernel_launch(void* const* d_in, const int* in_sizes, int n_in,
                              void* d_out, int out_size, void* d_ws, size_t ws_size,
                              hipStream_t stream) {
    const float* logits = (const float*)d_in[0];   // (32,1000,256) f32
    const int*   tcls   = (const int*)  d_in[1];   // (32,100) i32
    const float* sbox   = (const float*)d_in[2];   // (32,1000,4) f32
    const float* tbox   = (const float*)d_in[3];   // (32,100,4) f32
    float* out = (float*)d_out;                    // (32,) f32

    float* lse  = (float*)d_ws;                    // 32768 floats (32000 used)
    float* cost = lse + 32768;                     // 32*100*1024 floats (~12.8 MB)

    lse_kernel <<<NB * NSRC, 64,  0, stream>>>(logits, lse);
    cost_kernel<<<NB * NTGT, 256, 0, stream>>>(logits, tcls, sbox, tbox, lse, cost);
    lsa_kernel <<<NB,        64,  0, stream>>>(cost, out);
}

// Round 3
// 148.562 us; speedup vs baseline: 1.8962x; 1.4488x over previous
//
#include <hip/hip_runtime.h>
#include <math.h>

#define NSRC 1000
#define NTGT 100
#define NCLS 256
#define NB   32
#define NSP  1024                 // padded column count for LSA
#define PAD_IDX(j) ((j) + ((j) >> 4))
#define LDSN (NSP + (NSP >> 4))   // 1088 padded LDS entries

// ---------------- per-(b,s) logsumexp over 256 classes ----------------------
// 1000 blocks x 256 threads; each wave handles 8 consecutive rows.
__global__ __launch_bounds__(256) void lse_kernel(const float* __restrict__ logits,
                                                  float* __restrict__ lse) {
    int wid  = threadIdx.x >> 6;
    int lane = threadIdx.x & 63;
    int row0 = blockIdx.x * 32 + wid * 8;
    #pragma unroll 2
    for (int r = 0; r < 8; ++r) {
        int row = row0 + r;
        float4 v4 = reinterpret_cast<const float4*>(logits + (size_t)row * NCLS)[lane];
        float m = fmaxf(fmaxf(v4.x, v4.y), fmaxf(v4.z, v4.w));
        #pragma unroll
        for (int off = 32; off >= 1; off >>= 1) m = fmaxf(m, __shfl_xor(m, off));
        float s = expf(v4.x - m) + expf(v4.y - m) + expf(v4.z - m) + expf(v4.w - m);
        #pragma unroll
        for (int off = 32; off >= 1; off >>= 1) s += __shfl_xor(s, off);
        if (lane == 0) lse[row] = m + logf(s);
    }
}

// ---------------- transposed cost row + fused row-min reduction -------------
// One block per (b,t); b = blockIdx&31 so batch b's blocks share XCD b%8
// (logits slab cached once per XCD; cost rows written through the L2 that
// lsa block b will read). Also computes min/argmin of the row -> urow/jmin.
__global__ __launch_bounds__(256) void cost_kernel(const float* __restrict__ logits,
                                                   const int*   __restrict__ tcls,
                                                   const float* __restrict__ sbox,
                                                   const float* __restrict__ tbox,
                                                   const float* __restrict__ lse,
                                                   float*       __restrict__ cost,
                                                   float*       __restrict__ urow_g,
                                                   int*         __restrict__ jmin_g) {
    int b  = blockIdx.x & 31;
    int t  = blockIdx.x >> 5;
    int bt = b * NTGT + t;
    int cls = tcls[bt];
    float4 tb = reinterpret_cast<const float4*>(tbox)[bt];
    float area_t = (tb.z - tb.x) * (tb.w - tb.y);
    float* crow = cost + (size_t)bt * NSP;
    float m = 1e38f; int mi = 0x7fffffff;
    for (int s = threadIdx.x; s < NSP; s += 256) {
        if (s >= NSRC) { crow[s] = 1e30f; continue; }
        int gs = b * NSRC + s;
        float4 sb = reinterpret_cast<const float4*>(sbox)[gs];
        float ce = lse[gs] - logits[(size_t)gs * NCLS + cls];
        float ix1 = fmaxf(sb.x, tb.x), iy1 = fmaxf(sb.y, tb.y);
        float ix2 = fminf(sb.z, tb.z), iy2 = fminf(sb.w, tb.w);
        float inter = fmaxf(ix2 - ix1, 0.f) * fmaxf(iy2 - iy1, 0.f);
        float area_s = (sb.z - sb.x) * (sb.w - sb.y);
        float uni = area_s + area_t - inter;
        float iou = inter / uni;
        float cx1 = fminf(sb.x, tb.x), cy1 = fminf(sb.y, tb.y);
        float cx2 = fmaxf(sb.z, tb.z), cy2 = fmaxf(sb.w, tb.w);
        float carea = (cx2 - cx1) * (cy2 - cy1);
        float giou = iou - (carea - uni) / carea;
        float l1 = 0.25f * (fabsf(sb.x - tb.x) + fabsf(sb.y - tb.y) +
                            fabsf(sb.z - tb.z) + fabsf(sb.w - tb.w));
        float c = ce + 10.0f * (1.0f - giou) + l1;
        crow[s] = c;
        if (c < m) { m = c; mi = s; }
    }
    // wave reduce (min, argmin; lowest index on ties)
    #pragma unroll
    for (int off = 32; off >= 1; off >>= 1) {
        float om = __shfl_xor(m, off);
        int   oi = __shfl_xor(mi, off);
        if (om < m || (om == m && oi < mi)) { m = om; mi = oi; }
    }
    __shared__ float smin[4];
    __shared__ int   sidx[4];
    int wid = threadIdx.x >> 6, lane = threadIdx.x & 63;
    if (lane == 0) { smin[wid] = m; sidx[wid] = mi; }
    __syncthreads();
    if (threadIdx.x == 0) {
        #pragma unroll
        for (int w = 1; w < 4; ++w) {
            float om = smin[w]; int oi = sidx[w];
            if (om < m || (om == m && oi < mi)) { m = om; mi = oi; }
        }
        urow_g[bt] = m;
        jmin_g[bt] = mi;
    }
}

// ---------------- Jonker-Volgenant augmenting paths only --------------------
// One wave per batch. Phase 1 (row reduction) was fused into cost_kernel:
// here we load (urow, jmin), claim argmin columns, then run shortest
// augmenting paths only for collision-loser rows (~5-10 of 100).
__global__ __launch_bounds__(64) void lsa_kernel(const float* __restrict__ cost,
                                                 const float* __restrict__ urow_g,
                                                 const int*   __restrict__ jmin_g,
                                                 float* __restrict__ out) {
    int b    = blockIdx.x;
    int lane = threadIdx.x;
    const float* C = cost + (size_t)b * NTGT * NSP;
    __shared__ int   way[LDSN];     // pred chain; reused as claim[] first
    __shared__ int   pcol[LDSN];    // col -> assigned row
    __shared__ float uu[LDSN];      // col -> u of its assigned row
    __shared__ float urow[NTGT];    // row min (u dual)
    __shared__ int   jmin[NTGT];    // row argmin column
    __shared__ int   done[NTGT];    // assigned in claim phase?
    for (int t = lane; t < LDSN; t += 64) { pcol[t] = -1; uu[t] = 0.f; way[t] = 0x7fffffff; }
    for (int t = lane; t < NTGT; t += 64) {
        urow[t] = urow_g[b * NTGT + t];
        jmin[t] = jmin_g[b * NTGT + t];
    }
    float v[16], d[16];
    #pragma unroll
    for (int k = 0; k < 16; ++k) v[k] = 0.f;
    int base = lane * 16;
    __syncthreads();

    // ---- claim argmin columns (lowest row index wins)
    for (int r = lane; r < NTGT; r += 64) atomicMin(&way[PAD_IDX(jmin[r])], r);
    __syncthreads();
    for (int r = lane; r < NTGT; r += 64) {
        int j = jmin[r];
        int w = (way[PAD_IDX(j)] == r) ? 1 : 0;
        done[r] = w;
        if (w) { pcol[PAD_IDX(j)] = r; uu[PAD_IDX(j)] = urow[r]; }
    }
    __syncthreads();

    // ---- shortest augmenting path for unassigned rows
    for (int i = 0; i < NTGT; ++i) {
        if (done[i]) continue;                 // uniform across wave (LDS broadcast)
        float ui = urow[i];
        {
            const float4* row4 = reinterpret_cast<const float4*>(C + (size_t)i * NSP + base);
            #pragma unroll
            for (int q = 0; q < 4; ++q) {
                float4 c4 = row4[q];
                d[4*q+0] = c4.x - ui - v[4*q+0];
                d[4*q+1] = c4.y - ui - v[4*q+1];
                d[4*q+2] = c4.z - ui - v[4*q+2];
                d[4*q+3] = c4.w - ui - v[4*q+3];
            }
        }
        #pragma unroll
        for (int k = 0; k < 16; ++k) way[PAD_IDX(base + k)] = -1;
        unsigned int used = 0;
        float Df = 0.f;
        int jf = -1;

        for (int it = 0; it < NTGT + 3; ++it) {
            float lmin = 1e38f;
            #pragma unroll
            for (int k = 0; k < 16; ++k) {
                float val = ((used >> k) & 1u) ? 1e38f : d[k];
                lmin = fminf(lmin, val);
            }
            float wmin = lmin;
            #pragma unroll
            for (int off = 32; off >= 1; off >>= 1) wmin = fminf(wmin, __shfl_xor(wmin, off));
            unsigned long long msk = __ballot(lmin == wmin);
            int src = __ffsll(msk) - 1;
            int myk = -1;
            #pragma unroll
            for (int k = 15; k >= 0; --k)
                if (!((used >> k) & 1u) && d[k] == wmin) myk = k;
            int j0 = __shfl(base + myk, src);
            if (j0 < 0) break;                    // NaN safety net
            int pj0 = pcol[PAD_IDX(j0)];
            if (pj0 < 0) { Df = wmin; jf = j0; break; }   // reached a free column
            if ((j0 >> 4) == lane) used |= 1u << (j0 & 15);
            float uref = uu[PAD_IDX(j0)];
            float sft  = wmin - uref;             // dist(j0) - u[row(j0)]
            const float4* rr = reinterpret_cast<const float4*>(C + (size_t)pj0 * NSP + base);
            float cr[16];
            #pragma unroll
            for (int q = 0; q < 4; ++q) {
                float4 c4 = rr[q];
                cr[4*q+0] = c4.x; cr[4*q+1] = c4.y; cr[4*q+2] = c4.z; cr[4*q+3] = c4.w;
            }
            #pragma unroll
            for (int k = 0; k < 16; ++k) {
                float cand = sft + cr[k] - v[k];
                bool upd = (cand < d[k]) && !((used >> k) & 1u);
                if (upd) { d[k] = cand; way[PAD_IDX(base + k)] = j0; }
            }
        }

        // dual updates for scanned columns: v -= (Df - d), u[row] += (Df - d)
        if (jf >= 0) {
            #pragma unroll
            for (int k = 0; k < 16; ++k) {
                if ((used >> k) & 1u) {
                    float diff = Df - d[k];
                    v[k] -= diff;
                    uu[PAD_IDX(base + k)] += diff;
                }
            }
        }
        __syncthreads();
        // augment: walk predecessor chain, shifting rows (and their u) forward
        if (lane == 0 && jf >= 0) {
            int j = jf;
            for (int g = 0; g < NSP; ++g) {
                int jp = way[PAD_IDX(j)];
                if (jp < 0) { pcol[PAD_IDX(j)] = i; uu[PAD_IDX(j)] = ui + Df; break; }
                pcol[PAD_IDX(j)] = pcol[PAD_IDX(jp)];
                uu[PAD_IDX(j)]   = uu[PAD_IDX(jp)];
                j = jp;
            }
        }
        __syncthreads();
    }

    // mean of matched costs
    float acc = 0.f;
    #pragma unroll
    for (int k = 0; k < 16; ++k) {
        int j = base + k;
        if (j < NSRC) {
            int r = pcol[PAD_IDX(j)];
            if (r >= 0) acc += C[(size_t)r * NSP + j];
        }
    }
    #pragma unroll
    for (int off = 32; off >= 1; off >>= 1) acc += __shfl_xor(acc, off);
    if (lane == 0) out[b] = acc * (1.0f / NTGT);
}

extern "C" void kernel_launch(void* const* d_in, const int* in_sizes, int n_in,
                              void* d_out, int out_size, void* d_ws, size_t ws_size,
                              hipStream_t stream) {
    const float* logits = (const float*)d_in[0];   // (32,1000,256) f32
    const int*   tcls   = (const int*)  d_in[1];   // (32,100) i32
    const float* sbox   = (const float*)d_in[2];   // (32,1000,4) f32
    const float* tbox   = (const float*)d_in[3];   // (32,100,4) f32
    float* out = (float*)d_out;                    // (32,) f32

    float* lse    = (float*)d_ws;                  // 32768 floats (32000 used)
    float* cost   = lse + 32768;                   // 32*100*1024 floats (~13.1 MB)
    float* urow_g = cost + (size_t)NB * NTGT * NSP; // 3200 floats
    int*   jmin_g = (int*)(urow_g + NB * NTGT);     // 3200 ints

    lse_kernel <<<1000,      256, 0, stream>>>(logits, lse);
    cost_kernel<<<NB * NTGT, 256, 0, stream>>>(logits, tcls, sbox, tbox, lse, cost,
                                               urow_g, jmin_g);
    lsa_kernel <<<NB,        64,  0, stream>>>(cost, urow_g, jmin_g, out);
}